// Round 1
// 549.683 us; speedup vs baseline: 1.1366x; 1.1366x over previous
//
#include <hip/hip_runtime.h>

// AGG layer: out[n] = mean_{e: dst[e]==n} (src_emb[src[e]] + edge_emb[e]),  D=64 fp32.
// Round 6: (a) hist captures per-edge rank (atomicAdd return) -> scatter is
// atomic-free; (b) reduce reworked to quad-edge float4 form: lane l owns
// float4 column group (l&15) of edge j+(l>>4), so ONE dwordx4 wave-load
// fetches 4 edge rows (1 KB); two quads unrolled -> 4 KB in flight/wave.
// Addresses via __shfl (bpermute) instead of serial readlanes. Non-temporal
// loads on the single-use 320 MB edge stream keep src_emb hot in L2.
//
// ws ints: offsets[N+1] | counts[N] | rank[E] | blockSums[1024] | blockBase[1024]
//          | (pad to 8B) | pairs[E] (int2)

#define D 64
#define SCAN_BLK 1024   // elements per scan block (256 thr x 4)

typedef float f32x4 __attribute__((ext_vector_type(4)));

__global__ __launch_bounds__(256) void hist_kernel(
    const int* __restrict__ dst_idx, int* __restrict__ counts,
    int* __restrict__ rank, int E)
{
    int e = blockIdx.x * blockDim.x + threadIdx.x;
    if (e < E) rank[e] = atomicAdd(counts + dst_idx[e], 1);
}

__global__ __launch_bounds__(256) void scan_partial_kernel(
    const int* __restrict__ counts, int* __restrict__ blockSums, int N)
{
    __shared__ int red[256];
    const int t = threadIdx.x, b = blockIdx.x;
    const int base = b * SCAN_BLK + t * 4;
    int s = 0;
    #pragma unroll
    for (int k = 0; k < 4; ++k) { int i = base + k; if (i < N) s += counts[i]; }
    red[t] = s; __syncthreads();
    for (int off = 128; off; off >>= 1) {
        if (t < off) red[t] += red[t + off];
        __syncthreads();
    }
    if (t == 0) blockSums[b] = red[0];
}

__global__ __launch_bounds__(1024) void scan_sums_kernel(
    const int* __restrict__ blockSums, int* __restrict__ blockBase,
    int numBlocks, int* __restrict__ offsets, int N)
{
    __shared__ int s[1024];
    const int t = threadIdx.x;
    int v = (t < numBlocks) ? blockSums[t] : 0;
    s[t] = v; __syncthreads();
    for (int off = 1; off < 1024; off <<= 1) {
        int u = (t >= off) ? s[t - off] : 0;
        __syncthreads();
        if (t >= off) s[t] += u;
        __syncthreads();
    }
    if (t < numBlocks) blockBase[t] = (t == 0) ? 0 : s[t - 1];
    if (t == numBlocks - 1) offsets[N] = s[t];   // total == E
}

__global__ __launch_bounds__(256) void scan_final_kernel(
    const int* __restrict__ counts, const int* __restrict__ blockBase,
    int* __restrict__ offsets, int N)
{
    __shared__ int sc[256];
    const int t = threadIdx.x, b = blockIdx.x;
    const int base = b * SCAN_BLK + t * 4;
    int local[4];
    int s = 0;
    #pragma unroll
    for (int k = 0; k < 4; ++k) {
        int i = base + k;
        int c = (i < N) ? counts[i] : 0;
        local[k] = s; s += c;
    }
    sc[t] = s; __syncthreads();
    for (int off = 1; off < 256; off <<= 1) {
        int u = (t >= off) ? sc[t - off] : 0;
        __syncthreads();
        if (t >= off) sc[t] += u;
        __syncthreads();
    }
    const int thrBase = blockBase[b] + ((t == 0) ? 0 : sc[t - 1]);
    #pragma unroll
    for (int k = 0; k < 4; ++k) {
        int i = base + k;
        if (i < N) offsets[i] = thrBase + local[k];
    }
}

// Scatter {edge, src} pairs into dst-sorted order. Atomic-free: rank captured
// in hist. 1 thread/edge, 8 B random write.
__global__ __launch_bounds__(256) void pair_scatter_kernel(
    const int* __restrict__ src_idx,
    const int* __restrict__ dst_idx,
    const int* __restrict__ rank,
    const int* __restrict__ offsets,
    int2*      __restrict__ pairs,
    int E)
{
    int e = blockIdx.x * blockDim.x + threadIdx.x;
    if (e >= E) return;
    int pos = offsets[dst_idx[e]] + rank[e];
    pairs[pos] = make_int2(e, src_idx[e]);
}

// One wave (64 lanes) per node. Lane l owns float4 column group (l&15) of the
// (l>>4)-th edge of each quad. One dwordx4 wave-load = 4 edge rows (1 KB);
// two quads in flight. Cross-group reduce via shfl_xor(16,32) at the end.
__global__ __launch_bounds__(256) void reduce_kernel(
    const float* __restrict__ src_emb,
    const float* __restrict__ edge_emb,
    const int2*  __restrict__ pairs,
    const int*   __restrict__ offsets,
    float*       __restrict__ out,
    int N)
{
    const int wave = (blockIdx.x * blockDim.x + threadIdx.x) >> 6;
    const int lane = threadIdx.x & 63;
    if (wave >= N) return;

    const int beg = offsets[wave];
    const int end = offsets[wave + 1];
    const int grp = lane >> 4;          // which edge of the quad (0..3)
    const int cg  = (lane & 15) << 2;   // float column offset (0,4,..,60)

    f32x4 acc = {0.f, 0.f, 0.f, 0.f};

    for (int base = beg; base < end; base += 64) {
        const int cnt  = min(64, end - base);
        const int last = cnt - 1;
        int2 pr = make_int2(0, 0);
        if (lane < cnt) pr = pairs[base + lane];

        for (int j = 0; j < cnt; j += 8) {
            const int i0 = j + grp;
            const int i1 = i0 + 4;
            const bool v0 = (i0 <= last);
            const bool v1 = (i1 <= last);
            const int k0 = v0 ? i0 : last;   // clamp: loads always issue,
            const int k1 = v1 ? i1 : last;   // dup rows hit L1/L2
            const int e0 = __shfl(pr.x, k0);
            const int s0 = __shfl(pr.y, k0);
            const int e1 = __shfl(pr.x, k1);
            const int s1 = __shfl(pr.y, k1);

            f32x4 ev0 = __builtin_nontemporal_load(
                (const f32x4*)(edge_emb + ((size_t)e0 << 6) + cg));
            f32x4 sv0 = *(const f32x4*)(src_emb + ((size_t)s0 << 6) + cg);
            f32x4 ev1 = __builtin_nontemporal_load(
                (const f32x4*)(edge_emb + ((size_t)e1 << 6) + cg));
            f32x4 sv1 = *(const f32x4*)(src_emb + ((size_t)s1 << 6) + cg);

            f32x4 z = {0.f, 0.f, 0.f, 0.f};
            acc += v0 ? (ev0 + sv0) : z;
            acc += v1 ? (ev1 + sv1) : z;
        }
    }

    // sum the 4 edge-groups: lanes {l, l^16, l^32, l^48} share column group
    acc.x += __shfl_xor(acc.x, 16);
    acc.y += __shfl_xor(acc.y, 16);
    acc.z += __shfl_xor(acc.z, 16);
    acc.w += __shfl_xor(acc.w, 16);
    acc.x += __shfl_xor(acc.x, 32);
    acc.y += __shfl_xor(acc.y, 32);
    acc.z += __shfl_xor(acc.z, 32);
    acc.w += __shfl_xor(acc.w, 32);

    const int deg = end - beg;
    const float inv = (deg > 0) ? (1.0f / (float)deg) : 0.0f;
    if (grp == 0) {
        f32x4 r = acc * inv;
        __builtin_nontemporal_store(r, (f32x4*)(out + ((size_t)wave << 6) + cg));
    }
}

extern "C" void kernel_launch(void* const* d_in, const int* in_sizes, int n_in,
                              void* d_out, int out_size, void* d_ws, size_t ws_size,
                              hipStream_t stream) {
    const float* src_emb  = (const float*)d_in[0];   // [N, 64]
    const float* edge_emb = (const float*)d_in[1];   // [E, 64]
    const int*   src_idx  = (const int*)d_in[2];     // [E]
    const int*   dst_idx  = (const int*)d_in[3];     // [E]

    const int E = in_sizes[2];
    const int N = out_size / D;

    float* out = (float*)d_out;

    int* wsi       = (int*)d_ws;
    int* offsets   = wsi;                    // N+1
    int* counts    = offsets + (N + 1);      // N
    int* rank      = counts + N;             // E
    int* blockSums = rank + E;               // 1024
    int* blockBase = blockSums + 1024;       // 1024
    size_t hdr = (size_t)(N + 1) + N + E + 1024 + 1024;
    hdr = (hdr + 1) & ~(size_t)1;            // 8-B align pairs
    int2* pairs = (int2*)(wsi + hdr);        // E int2

    const int numBlocks = (N + SCAN_BLK - 1) / SCAN_BLK;

    (void)hipMemsetAsync(counts, 0, (size_t)N * sizeof(int), stream);
    hist_kernel<<<(E + 255) / 256, 256, 0, stream>>>(dst_idx, counts, rank, E);
    scan_partial_kernel<<<numBlocks, 256, 0, stream>>>(counts, blockSums, N);
    scan_sums_kernel<<<1, 1024, 0, stream>>>(blockSums, blockBase, numBlocks, offsets, N);
    scan_final_kernel<<<numBlocks, 256, 0, stream>>>(counts, blockBase, offsets, N);

    pair_scatter_kernel<<<(E + 255) / 256, 256, 0, stream>>>(src_idx, dst_idx,
                                                             rank, offsets, pairs, E);
    {
        // 4 waves per 256-thread block, one wave per node
        int grid = (N + 3) / 4;
        reduce_kernel<<<grid, 256, 0, stream>>>(src_emb, edge_emb, pairs,
                                                offsets, out, N);
    }
}